// Round 7
// baseline (811.617 us; speedup 1.0000x reference)
//
#include <hip/hip_runtime.h>
#include <hip/hip_bf16.h>
#include <cstdint>

typedef __bf16 bf16x8 __attribute__((ext_vector_type(8)));
typedef __bf16 bf16x4 __attribute__((ext_vector_type(4)));
typedef short  short4v __attribute__((ext_vector_type(4)));
typedef _Float16 f16x4 __attribute__((ext_vector_type(4)));
typedef float f32x4 __attribute__((ext_vector_type(4)));

union U128 { uint4 u; __bf16 h[8]; };
union U64  { uint2 u; __bf16 h[4]; };
union PV4  { uint2 u; bf16x4 b; short4v s; f16x4 f; };

#define DMODEL 1024
#define NHEAD  16
#define DHEAD  64

// ---- 16x16x16 MFMA selection for the PV step (P/V as 4x16-bit per lane) ----
#if __has_builtin(__builtin_amdgcn_mfma_f32_16x16x16_bf16)
#define PV_F16 0
__device__ __forceinline__ f32x4 mfma16(PV4 a, PV4 b, f32x4 c) {
  return __builtin_amdgcn_mfma_f32_16x16x16_bf16(a.b, b.b, c, 0, 0, 0);
}
#elif __has_builtin(__builtin_amdgcn_mfma_f32_16x16x16bf16_1k)
#define PV_F16 0
__device__ __forceinline__ f32x4 mfma16(PV4 a, PV4 b, f32x4 c) {
  return __builtin_amdgcn_mfma_f32_16x16x16bf16_1k(a.s, b.s, c, 0, 0, 0);
}
#else
#define PV_F16 1
__device__ __forceinline__ f32x4 mfma16(PV4 a, PV4 b, f32x4 c) {
  return __builtin_amdgcn_mfma_f32_16x16x16f16(a.f, b.f, c, 0, 0, 0);
}
#endif

__device__ __forceinline__ uint16_t pv_bits(__bf16 v) {
#if PV_F16
  union { _Float16 f; uint16_t u; } x; x.f = (_Float16)(float)v; return x.u;
#else
  union { __bf16 b; uint16_t u; } x; x.b = v; return x.u;
#endif
}

__device__ __forceinline__ PV4 pack4(float a, float b, float c, float d) {
  PV4 r;
#if PV_F16
  r.f = (f16x4){(_Float16)a, (_Float16)b, (_Float16)c, (_Float16)d};
#else
  r.b = (bf16x4){(__bf16)a, (__bf16)b, (__bf16)c, (__bf16)d};
#endif
  return r;
}

__device__ __forceinline__ void async_copy16(const void* g, void* l) {
  __builtin_amdgcn_global_load_lds(
      (const __attribute__((address_space(1))) void*)g,
      (__attribute__((address_space(3))) void*)l, 16, 0, 0);
}

// ---------------- fused fp32 -> bf16 cast of two buffers ----------------
__global__ __launch_bounds__(256) void k_cast2(const float* __restrict__ a,
    const float* __restrict__ b, __bf16* __restrict__ da,
    __bf16* __restrict__ db, int n) {
  int i = (blockIdx.x * 256 + threadIdx.x) * 4;
  const float* s = a; __bf16* d = da;
  if (i >= n) { s = b; d = db; i -= n; }
  float4 v = *(const float4*)(s + i);
  U64 o;
  o.h[0] = (__bf16)v.x; o.h[1] = (__bf16)v.y;
  o.h[2] = (__bf16)v.z; o.h[3] = (__bf16)v.w;
  *(uint2*)(d + i) = o.u;
}

// ---------------- pack up to 3 fp32 bias vectors (n each) into dst ----------------
__global__ __launch_bounds__(256) void k_pack(float* __restrict__ dst,
    const float* __restrict__ s0, const float* __restrict__ s1,
    const float* __restrict__ s2, int n) {
  int i = blockIdx.x * 256 + threadIdx.x;
  if (i < n) dst[i] = s0[i];
  else if (i < 2 * n) dst[i] = s1[i - n];
  else if (i < 3 * n) dst[i] = s2[i - 2 * n];
}

// ------------- batched 32x32 transpose + cast: src[z][R][C] f32 -> dst[z][C][R] bf16 -------------
__global__ __launch_bounds__(256) void k_transpose(const float* __restrict__ src,
    __bf16* __restrict__ dst, int R, int C) {
  __shared__ __bf16 tile[32][33];
  src += (size_t)blockIdx.z * R * C;
  dst += (size_t)blockIdx.z * R * C;
  int c0 = blockIdx.x * 32, r0 = blockIdx.y * 32;
  int tx = threadIdx.x & 31, ty = threadIdx.x >> 5;
  for (int i = ty; i < 32; i += 8)
    tile[i][tx] = (__bf16)src[(size_t)(r0 + i) * C + (c0 + tx)];
  __syncthreads();
  for (int i = ty; i < 32; i += 8)
    dst[(size_t)(c0 + i) * R + (r0 + tx)] = tile[tx][i];
}

// ------------- 3-source per-head transpose: srcN[16][R][C] f32 -> dst[z][C][R] bf16, z=src*16+head
__global__ __launch_bounds__(256) void k_transpose3(const float* __restrict__ s0,
    const float* __restrict__ s1, const float* __restrict__ s2,
    __bf16* __restrict__ dst, int R, int C) {
  __shared__ __bf16 tile[32][33];
  int z = blockIdx.z;
  const float* src = (z < 16) ? s0 : (z < 32) ? s1 : s2;
  src += (size_t)(z & 15) * R * C;
  dst += (size_t)z * R * C;
  int c0 = blockIdx.x * 32, r0 = blockIdx.y * 32;
  int tx = threadIdx.x & 31, ty = threadIdx.x >> 5;
  for (int i = ty; i < 32; i += 8)
    tile[i][tx] = (__bf16)src[(size_t)(r0 + i) * C + (c0 + tx)];
  __syncthreads();
  for (int i = ty; i < 32; i += 8)
    dst[(size_t)(c0 + i) * R + (r0 + tx)] = tile[tx][i];
}

// ------------- V^T pre-pass: V[b][l][h*64+dv] (stride kvs) -> VT[b*16+h][dv][L] (PV dtype) -------
// Makes PV fragments single uint2 global loads (L2-resident: 128 KB/head) and lets
// k_attn drop the V LDS staging entirely (LDS 36.8->18.4 KB => 8 blocks/CU).
__global__ __launch_bounds__(256) void k_vt(const __bf16* __restrict__ V,
    uint16_t* __restrict__ VT, int L, int kvs) {
  __shared__ uint16_t tile[32][33];
  const int z = blockIdx.z, b = z >> 4, h = z & 15;
  const __bf16* src = V + (size_t)b * L * kvs + h * DHEAD;
  uint16_t* dst = VT + (size_t)z * DHEAD * L;
  const int l0 = blockIdx.x * 32, d0 = blockIdx.y * 32;
  const int tx = threadIdx.x & 31, ty = threadIdx.x >> 5;
  for (int i = ty; i < 32; i += 8)
    tile[i][tx] = pv_bits(src[(size_t)(l0 + i) * kvs + d0 + tx]);
  __syncthreads();
  for (int i = ty; i < 32; i += 8)
    dst[(size_t)(d0 + i) * L + l0 + tx] = tile[tx][i];
}

// ---------------- bf16 TN GEMM: C[M,N] = A[M,K] * Bt[N,K]^T + bias ----------------
// 128x128 tile, BK=64, global_load_lds staging, 16B-granule XOR swizzle.
// PERF LEDGER: T1 XCD block-swizzle tried in round 4: +30us total (~4-5%/GEMM
// regression). These GEMM working sets (A 16MB + B <=8MB + C <=48MB) are
// L3-resident — wrong regime for T1 (guide m160: costs ~2% when L3-fit).
template<bool RELU, typename OutT>
__global__ __launch_bounds__(256, 3) void k_gemm(const __bf16* __restrict__ A,
    const __bf16* __restrict__ Bt, const float* __restrict__ bias,
    OutT* __restrict__ C, int M, int N, int K) {
  __shared__ __bf16 As[128][64];
  __shared__ __bf16 Bs[128][64];
  const int m0 = blockIdx.y * 128, n0 = blockIdx.x * 128;
  const int t = threadIdx.x;
  const int wave = t >> 6, lane = t & 63;
  const int wm = (wave & 1) * 64, wn = (wave >> 1) * 64;
  const int lrow = lane & 15, quad = lane >> 4;
  const int r8 = lane >> 3;
  const int gG = (lane & 7) ^ (r8 & 7);
  const __bf16* Ap[4]; const __bf16* Bp[4];
  __bf16* lA[4]; __bf16* lB[4];
  for (int j = 0; j < 4; j++) {
    int rr = wave * 8 + j * 32 + r8;
    Ap[j] = A  + (size_t)(m0 + rr) * K + gG * 8;
    Bp[j] = Bt + (size_t)(n0 + rr) * K + gG * 8;
    lA[j] = &As[wave * 8 + j * 32][0];
    lB[j] = &Bs[wave * 8 + j * 32][0];
  }
  f32x4 acc[4][4] = {};
  for (int k0 = 0; k0 < K; k0 += 64) {
    __syncthreads();
    for (int j = 0; j < 4; j++) {
      async_copy16(Ap[j] + k0, lA[j]);
      async_copy16(Bp[j] + k0, lB[j]);
    }
    __syncthreads();
    for (int ks = 0; ks < 2; ks++) {
      bf16x8 af[4], bfv[4];
      for (int i = 0; i < 4; i++) {
        int ra = wm + i * 16 + lrow, rb = wn + i * 16 + lrow;
        af[i]  = *(const bf16x8*)&As[ra][(((ks * 4 + quad) ^ (ra & 7))) * 8];
        bfv[i] = *(const bf16x8*)&Bs[rb][(((ks * 4 + quad) ^ (rb & 7))) * 8];
      }
      for (int mi = 0; mi < 4; mi++)
        for (int ni = 0; ni < 4; ni++)
          acc[mi][ni] = __builtin_amdgcn_mfma_f32_16x16x32_bf16(af[mi], bfv[ni], acc[mi][ni], 0, 0, 0);
    }
  }
  for (int ni = 0; ni < 4; ni++) {
    int col = n0 + wn + ni * 16 + lrow;
    float bv = bias[col];
    for (int mi = 0; mi < 4; mi++) {
      int row = m0 + wm + mi * 16 + quad * 4;
      for (int r = 0; r < 4; r++) {
        float v = acc[mi][ni][r] + bv;
        if (RELU) v = fmaxf(v, 0.f);
        C[(size_t)(row + r) * N + col] = (OutT)v;
      }
    }
  }
}

// ---------------- fused flash attention v4: V from pre-transposed global ----------
// grid (Lq/128, B*H). Causal: block bx covers q-tiles (bx, NT-1-bx); cross: (2bx, 2bx+1).
// Each wave: 16 q-rows per tile. Softmax in exp2 domain (scale*log2e folded into Q).
// v4 change: V LDS staging dropped; PV reads V^T fragments (uint2) straight from
// the k_vt pre-pass buffer (L2-resident, 128 KB/head shared by 8 blocks). Removes
// V prefetch regs + 16 pv_bits + 16 ds_write per tile; halves LDS -> 8 blocks/CU.
// PERF LEDGER (all harness-measured; do not re-try without new mechanism):
//  - vfr[4][4] V-frag hoist across f: spill, +350MB HBM r/w, 101->231us (r2).
//  - s_setprio around MFMA clusters: spill via code-motion barrier, 101->162us (r3).
//  - deferred l-sum (epilogue reduce): +112MB FETCH, 101->131us (r5) — removing
//    the in-loop shuffle serialization lets f=0/f=1 live ranges overlap -> spill.
//  - permlane16_swap max-reduce + defer-max (r1, bundled): absmax fail 0.36.
//  => the softmax/PV region is at a register knife edge. In-loop shuffles stay.
template<bool CAUSAL>
__global__ __launch_bounds__(256, 4) void k_attn(const __bf16* __restrict__ Q,
    const __bf16* __restrict__ Kg, const uint16_t* __restrict__ VT,
    float* __restrict__ O, int Lq, int Lk, int qs, int kvs) {
  __shared__ alignas(16) __bf16 Ks[2][64][72];
  const int t = threadIdx.x;
  const int wave = t >> 6, lane = t & 63;
  const int lrow = lane & 15, quad = lane >> 4;
  const int wm16 = wave * 16;
  int qt[2];
  if (CAUSAL) { qt[0] = blockIdx.x; qt[1] = gridDim.x * 2 - 1 - blockIdx.x; }
  else        { qt[0] = blockIdx.x * 2; qt[1] = qt[0] + 1; }
  const int b = blockIdx.y >> 4, h = blockIdx.y & 15;
  const __bf16* Qb = Q  + (size_t)b * Lq * qs  + h * DHEAD;
  const __bf16* Kb = Kg + (size_t)b * Lk * kvs + h * DHEAD;
  const uint16_t* VTb = VT + (size_t)blockIdx.y * DHEAD * Lk;
  // Q B-fragments, scale folded: 0.125 * log2(e) (softmax done in exp2 domain)
  const float qsc = 0.125f * 1.44269504f;
  bf16x8 qf[2][2];
  for (int f = 0; f < 2; f++)
    for (int ks = 0; ks < 2; ks++) {
      U128 u;
      u.u = *(const uint4*)(Qb + (size_t)(qt[f] * 64 + wm16 + lrow) * qs + ks * 32 + quad * 8);
      for (int j = 0; j < 8; j++) u.h[j] = (__bf16)((float)u.h[j] * qsc);
      qf[f][ks] = *(const bf16x8*)u.h;
    }
  const int nkt = CAUSAL ? (qt[1] + 1) : (Lk / 64);
  const int krow = t >> 3, kcol = (t & 7) * 8;
  f32x4 acc_o[2][4] = {};       // O^T per frag: row vd=ni*16+quad*4+r, col q=lrow
  float m_r[2] = {-1e30f, -1e30f}, l_r[2] = {0.f, 0.f};
  uint4 ka, ka2;
  ka  = *(const uint4*)(Kb + (size_t)krow * kvs + kcol);
  ka2 = *(const uint4*)(Kb + (size_t)(krow + 32) * kvs + kcol);
  int c = 0;
  for (int kt = 0; kt < nkt; kt++) {
    const int kn = (kt + 1 < nkt) ? (kt + 1) * 64 : kt * 64;
    uint4 na  = *(const uint4*)(Kb + (size_t)(kn + krow) * kvs + kcol);
    uint4 na2 = *(const uint4*)(Kb + (size_t)(kn + krow + 32) * kvs + kcol);
    *(uint4*)&Ks[c][krow][kcol]      = ka;
    *(uint4*)&Ks[c][krow + 32][kcol] = ka2;
    __syncthreads();
    for (int f = 0; f < 2; f++) {
      if (CAUSAL && kt > qt[f]) continue;   // wave-uniform: fully-masked sub-tile
      // S^T = K Q^T : C-layout row k=nb*16+quad*4+r, col q=lrow  (exp2 domain)
      f32x4 st[4] = {};
      for (int ks = 0; ks < 2; ks++)
        for (int nb = 0; nb < 4; nb++) {
          bf16x8 kf = *(const bf16x8*)&Ks[c][nb * 16 + lrow][ks * 32 + quad * 8];
          st[nb] = __builtin_amdgcn_mfma_f32_16x16x32_bf16(kf, qf[f][ks], st[nb], 0, 0, 0);
        }
      float pm = -1e30f;
      for (int nb = 0; nb < 4; nb++)
        for (int r = 0; r < 4; r++) {
          float s = st[nb][r];
          if (CAUSAL && kt == qt[f])
            if (nb * 16 + quad * 4 + r > wm16 + lrow) s = -1e30f;
          st[nb][r] = s;
          pm = fmaxf(pm, s);
        }
      pm = fmaxf(pm, __shfl_xor(pm, 16));
      pm = fmaxf(pm, __shfl_xor(pm, 32));
      float mn = fmaxf(m_r[f], pm);
      float alpha = exp2f(m_r[f] - mn);
      m_r[f] = mn;
      float rs = 0.f;
      PV4 pf[4];
      for (int nb = 0; nb < 4; nb++) {
        float p0 = exp2f(st[nb][0] - mn), p1 = exp2f(st[nb][1] - mn);
        float p2 = exp2f(st[nb][2] - mn), p3 = exp2f(st[nb][3] - mn);
        rs += (p0 + p1) + (p2 + p3);
        pf[nb] = pack4(p0, p1, p2, p3);
      }
      rs += __shfl_xor(rs, 16);
      rs += __shfl_xor(rs, 32);
      l_r[f] = l_r[f] * alpha + rs;
      for (int ni = 0; ni < 4; ni++)
        for (int r = 0; r < 4; r++) acc_o[f][ni][r] *= alpha;
      // O^T += V^T P^T  (A = V^T frag from global/L2 uint2, B = P frag from registers)
      for (int nb = 0; nb < 4; nb++)
        for (int ni = 0; ni < 4; ni++) {
          PV4 vf;
          vf.u = *(const uint2*)(VTb + (size_t)(ni * 16 + lrow) * Lk
                                 + kt * 64 + nb * 16 + quad * 4);
          acc_o[f][ni] = mfma16(vf, pf[nb], acc_o[f][ni]);
        }
    }
    ka = na; ka2 = na2;
    c ^= 1;
  }
  for (int f = 0; f < 2; f++) {
    const float linv = 1.f / fmaxf(l_r[f], 1e-30f);
    float* orow = O + (size_t)b * Lq * DMODEL
                + (size_t)(qt[f] * 64 + wm16 + lrow) * DMODEL + h * DHEAD;
    for (int ni = 0; ni < 4; ni++) {
      float4 v = { acc_o[f][ni][0] * linv, acc_o[f][ni][1] * linv,
                   acc_o[f][ni][2] * linv, acc_o[f][ni][3] * linv };
      *(float4*)(orow + ni * 16 + quad * 4) = v;
    }
  }
}

// ---------------- residual(ResT + fp32) + LayerNorm -> OutT ----------------
template<typename ResT, typename OutT>
__global__ __launch_bounds__(256) void k_ln_add(const ResT* __restrict__ a,
    const float* __restrict__ bres, const float* __restrict__ g,
    const float* __restrict__ be, OutT* __restrict__ out) {
  __shared__ float red[2][4];
  const int r = blockIdx.x, t = threadIdx.x;
  const size_t base = (size_t)r * DMODEL + t * 4;
  float x[4];
  for (int i = 0; i < 4; i++) x[i] = (float)a[base + i] + bres[base + i];
  float s  = x[0] + x[1] + x[2] + x[3];
  float s2 = x[0]*x[0] + x[1]*x[1] + x[2]*x[2] + x[3]*x[3];
  for (int off = 32; off > 0; off >>= 1) {
    s  += __shfl_down(s, off);
    s2 += __shfl_down(s2, off);
  }
  if ((t & 63) == 0) { red[0][t >> 6] = s; red[1][t >> 6] = s2; }
  __syncthreads();
  s  = red[0][0] + red[0][1] + red[0][2] + red[0][3];
  s2 = red[1][0] + red[1][1] + red[1][2] + red[1][3];
  const float mean = s * (1.f / DMODEL);
  const float var  = s2 * (1.f / DMODEL) - mean * mean;
  const float rstd = rsqrtf(var + 1e-5f);
  for (int i = 0; i < 4; i++)
    out[base + i] = (OutT)((x[i] - mean) * rstd * g[t * 4 + i] + be[t * 4 + i]);
}

extern "C" void kernel_launch(void* const* d_in, const int* in_sizes, int n_in,
                              void* d_out, int out_size, void* d_ws, size_t ws_size,
                              hipStream_t stream) {
  (void)in_sizes; (void)n_in; (void)out_size; (void)ws_size;
  const float* dec   = (const float*)d_in[0];
  const float* enc   = (const float*)d_in[1];
  const float* m_wq  = (const float*)d_in[2];
  const float* m_bq  = (const float*)d_in[3];
  const float* m_wk  = (const float*)d_in[4];
  const float* m_bk  = (const float*)d_in[5];
  const float* m_wv  = (const float*)d_in[6];
  const float* m_bv  = (const float*)d_in[7];
  const float* c_wq  = (const float*)d_in[8];
  const float* c_bq  = (const float*)d_in[9];
  const float* c_wk  = (const float*)d_in[10];
  const float* c_bk  = (const float*)d_in[11];
  const float* c_wv  = (const float*)d_in[12];
  const float* c_bv  = (const float*)d_in[13];
  const float* ff_w1 = (const float*)d_in[14];
  const float* ff_b1 = (const float*)d_in[15];
  const float* ff_w2 = (const float*)d_in[16];
  const float* ff_b2 = (const float*)d_in[17];
  const float* ln1_g = (const float*)d_in[18];
  const float* ln1_b = (const float*)d_in[19];
  const float* ln2_g = (const float*)d_in[20];
  const float* ln2_b = (const float*)d_in[21];

  // workspace (136 MB):
  //  [0,16)   decB -> X1b          [16,32)  encB -> X2b
  //  [32,40)  WB weights (bf16); fp32 bias pack at +38MB
  //  [40,88)  QKV (self) | [40,72) KV (cross) + [72,88) Qc | [40,104) FF
  //  [88,104) VT (V^T pre-pass, 16 MB) — dead before FF overlays it
  //  [104,136) AO (fp32)
  char* w = (char*)d_ws;
  __bf16* decB = (__bf16*)(w);
  __bf16* encB = (__bf16*)(w + (16ull << 20));
  __bf16* X1b  = decB;
  __bf16* X2b  = encB;
  __bf16* WB   = (__bf16*)(w + (32ull << 20));
  float*  BP   = (float*) (w + (38ull << 20));
  __bf16* QKV  = (__bf16*)(w + (40ull << 20));
  __bf16* KV   = (__bf16*)(w + (40ull << 20));
  __bf16* Qc   = (__bf16*)(w + (72ull << 20));
  __bf16* FF   = (__bf16*)(w + (40ull << 20));
  uint16_t* VTw = (uint16_t*)(w + (88ull << 20));
  float*  AO   = (float*) (w + (104ull << 20));
  float* out = (float*)d_out;

  const int M = 8192, NTOK = M * DMODEL;
  dim3 blk(256);
  dim3 gT3(2, 32, 48);    // 3-source per-head weight transpose
  dim3 gA(8, 128);        // attention: 2 q-tiles per block
  dim3 gV(32, 2, 128);    // V^T pre-pass
  dim3 gL(M);

  k_cast2<<<dim3(2 * NTOK / 1024), blk, 0, stream>>>(dec, enc, decB, encB, NTOK);

  // ---- masked self-attention: fused QKV projection (N=3072) ----
  k_transpose3<<<gT3, blk, 0, stream>>>(m_wq, m_wk, m_wv, WB, 1024, 64);
  k_pack<<<dim3(12), blk, 0, stream>>>(BP, m_bq, m_bk, m_bv, 1024);
  k_gemm<false, __bf16><<<dim3(24, 64), blk, 0, stream>>>(decB, WB, BP, QKV, M, 3072, 1024);
  k_vt<<<gV, blk, 0, stream>>>(QKV + 2048, VTw, 1024, 3072);
  k_attn<true><<<gA, blk, 0, stream>>>(QKV, QKV + 1024, VTw, AO, 1024, 1024, 3072, 3072);
  k_ln_add<float, __bf16><<<gL, blk, 0, stream>>>(dec, AO, ln1_g, ln1_b, X1b);  // decB dead

  // ---- cross-attention: fused KV (N=2048, enc) + Q (X1b) ----
  k_transpose3<<<gT3, blk, 0, stream>>>(c_wk, c_wv, c_wq, WB, 1024, 64);
  k_pack<<<dim3(8), blk, 0, stream>>>(BP, c_bk, c_bv, c_bv, 1024);
  k_gemm<false, __bf16><<<dim3(16, 64), blk, 0, stream>>>(encB, WB, BP, KV, M, 2048, 1024);
  k_vt<<<gV, blk, 0, stream>>>(KV + 1024, VTw, 1024, 2048);
  k_gemm<false, __bf16><<<dim3(8, 64), blk, 0, stream>>>(X1b, WB + (2 << 20), c_bq, Qc, M, 1024, 1024);
  k_attn<false><<<gA, blk, 0, stream>>>(Qc, KV, VTw, AO, 1024, 1024, 1024, 2048);
  k_ln_add<__bf16, __bf16><<<gL, blk, 0, stream>>>(X1b, AO, ln2_g, ln2_b, X2b);  // encB dead

  // ---- FFN (QKV/KV/Qc/VT dead -> FF overlays [40,104)) ----
  k_transpose<<<dim3(128, 32, 1), blk, 0, stream>>>(ff_w1, WB, 1024, 4096);
  k_gemm<true, __bf16><<<dim3(32, 64), blk, 0, stream>>>(X2b, WB, ff_b1, FF, M, 4096, 1024);
  k_transpose<<<dim3(32, 128, 1), blk, 0, stream>>>(ff_w2, WB, 4096, 1024);
  k_gemm<false, float><<<dim3(8, 64), blk, 0, stream>>>(FF, WB, ff_b2, AO, M, 1024, 4096);
  k_ln_add<__bf16, float><<<gL, blk, 0, stream>>>(X2b, AO, ln2_g, ln2_b, out);
}

// Round 9
// 691.689 us; speedup vs baseline: 1.1734x; 1.1734x over previous
//
#include <hip/hip_runtime.h>
#include <hip/hip_bf16.h>
#include <cstdint>

typedef __bf16 bf16x8 __attribute__((ext_vector_type(8)));
typedef __bf16 bf16x4 __attribute__((ext_vector_type(4)));
typedef short  short4v __attribute__((ext_vector_type(4)));
typedef _Float16 f16x4 __attribute__((ext_vector_type(4)));
typedef float f32x4 __attribute__((ext_vector_type(4)));

union U128 { uint4 u; __bf16 h[8]; };
union U64  { uint2 u; __bf16 h[4]; };
union PV4  { uint2 u; bf16x4 b; short4v s; f16x4 f; };

#define DMODEL 1024
#define NHEAD  16
#define DHEAD  64

// ---- 16x16x16 MFMA selection for the PV step (P/V as 4x16-bit per lane) ----
#if __has_builtin(__builtin_amdgcn_mfma_f32_16x16x16_bf16)
#define PV_F16 0
__device__ __forceinline__ f32x4 mfma16(PV4 a, PV4 b, f32x4 c) {
  return __builtin_amdgcn_mfma_f32_16x16x16_bf16(a.b, b.b, c, 0, 0, 0);
}
#elif __has_builtin(__builtin_amdgcn_mfma_f32_16x16x16bf16_1k)
#define PV_F16 0
__device__ __forceinline__ f32x4 mfma16(PV4 a, PV4 b, f32x4 c) {
  return __builtin_amdgcn_mfma_f32_16x16x16bf16_1k(a.s, b.s, c, 0, 0, 0);
}
#else
#define PV_F16 1
__device__ __forceinline__ f32x4 mfma16(PV4 a, PV4 b, f32x4 c) {
  return __builtin_amdgcn_mfma_f32_16x16x16f16(a.f, b.f, c, 0, 0, 0);
}
#endif

__device__ __forceinline__ uint16_t pv_bits(__bf16 v) {
#if PV_F16
  union { _Float16 f; uint16_t u; } x; x.f = (_Float16)(float)v; return x.u;
#else
  union { __bf16 b; uint16_t u; } x; x.b = v; return x.u;
#endif
}

__device__ __forceinline__ PV4 pack4(float a, float b, float c, float d) {
  PV4 r;
#if PV_F16
  r.f = (f16x4){(_Float16)a, (_Float16)b, (_Float16)c, (_Float16)d};
#else
  r.b = (bf16x4){(__bf16)a, (__bf16)b, (__bf16)c, (__bf16)d};
#endif
  return r;
}

__device__ __forceinline__ void async_copy16(const void* g, void* l) {
  __builtin_amdgcn_global_load_lds(
      (const __attribute__((address_space(1))) void*)g,
      (__attribute__((address_space(3))) void*)l, 16, 0, 0);
}

// ---------------- fused fp32 -> bf16 cast of two buffers ----------------
__global__ __launch_bounds__(256) void k_cast2(const float* __restrict__ a,
    const float* __restrict__ b, __bf16* __restrict__ da,
    __bf16* __restrict__ db, int n) {
  int i = (blockIdx.x * 256 + threadIdx.x) * 4;
  const float* s = a; __bf16* d = da;
  if (i >= n) { s = b; d = db; i -= n; }
  float4 v = *(const float4*)(s + i);
  U64 o;
  o.h[0] = (__bf16)v.x; o.h[1] = (__bf16)v.y;
  o.h[2] = (__bf16)v.z; o.h[3] = (__bf16)v.w;
  *(uint2*)(d + i) = o.u;
}

// ---------------- pack up to 3 fp32 bias vectors (n each) into dst ----------------
__global__ __launch_bounds__(256) void k_pack(float* __restrict__ dst,
    const float* __restrict__ s0, const float* __restrict__ s1,
    const float* __restrict__ s2, int n) {
  int i = blockIdx.x * 256 + threadIdx.x;
  if (i < n) dst[i] = s0[i];
  else if (i < 2 * n) dst[i] = s1[i - n];
  else if (i < 3 * n) dst[i] = s2[i - 2 * n];
}

// ------------- batched 32x32 transpose + cast: src[z][R][C] f32 -> dst[z][C][R] bf16 -------------
__global__ __launch_bounds__(256) void k_transpose(const float* __restrict__ src,
    __bf16* __restrict__ dst, int R, int C) {
  __shared__ __bf16 tile[32][33];
  src += (size_t)blockIdx.z * R * C;
  dst += (size_t)blockIdx.z * R * C;
  int c0 = blockIdx.x * 32, r0 = blockIdx.y * 32;
  int tx = threadIdx.x & 31, ty = threadIdx.x >> 5;
  for (int i = ty; i < 32; i += 8)
    tile[i][tx] = (__bf16)src[(size_t)(r0 + i) * C + (c0 + tx)];
  __syncthreads();
  for (int i = ty; i < 32; i += 8)
    dst[(size_t)(c0 + i) * R + (r0 + tx)] = tile[tx][i];
}

// ------------- 3-source per-head transpose: srcN[16][R][C] f32 -> dst[z][C][R] bf16, z=src*16+head
__global__ __launch_bounds__(256) void k_transpose3(const float* __restrict__ s0,
    const float* __restrict__ s1, const float* __restrict__ s2,
    __bf16* __restrict__ dst, int R, int C) {
  __shared__ __bf16 tile[32][33];
  int z = blockIdx.z;
  const float* src = (z < 16) ? s0 : (z < 32) ? s1 : s2;
  src += (size_t)(z & 15) * R * C;
  dst += (size_t)z * R * C;
  int c0 = blockIdx.x * 32, r0 = blockIdx.y * 32;
  int tx = threadIdx.x & 31, ty = threadIdx.x >> 5;
  for (int i = ty; i < 32; i += 8)
    tile[i][tx] = (__bf16)src[(size_t)(r0 + i) * C + (c0 + tx)];
  __syncthreads();
  for (int i = ty; i < 32; i += 8)
    dst[(size_t)(c0 + i) * R + (r0 + tx)] = tile[tx][i];
}

// ---------------- bf16 TN GEMM: C[M,N] = A[M,K] * Bt[N,K]^T + bias ----------------
// 128x128 tile, BK=64, global_load_lds staging, 16B-granule XOR swizzle.
// Used for N=1024 shapes (Qc, FF2) where a 256-tile grid would leave half the CUs idle.
// PERF LEDGER: T1 XCD block-swizzle (round 4): +30us total — L3-resident regime, reverted.
template<bool RELU, typename OutT>
__global__ __launch_bounds__(256, 3) void k_gemm(const __bf16* __restrict__ A,
    const __bf16* __restrict__ Bt, const float* __restrict__ bias,
    OutT* __restrict__ C, int M, int N, int K) {
  __shared__ __bf16 As[128][64];
  __shared__ __bf16 Bs[128][64];
  const int m0 = blockIdx.y * 128, n0 = blockIdx.x * 128;
  const int t = threadIdx.x;
  const int wave = t >> 6, lane = t & 63;
  const int wm = (wave & 1) * 64, wn = (wave >> 1) * 64;
  const int lrow = lane & 15, quad = lane >> 4;
  const int r8 = lane >> 3;
  const int gG = (lane & 7) ^ (r8 & 7);
  const __bf16* Ap[4]; const __bf16* Bp[4];
  __bf16* lA[4]; __bf16* lB[4];
  for (int j = 0; j < 4; j++) {
    int rr = wave * 8 + j * 32 + r8;
    Ap[j] = A  + (size_t)(m0 + rr) * K + gG * 8;
    Bp[j] = Bt + (size_t)(n0 + rr) * K + gG * 8;
    lA[j] = &As[wave * 8 + j * 32][0];
    lB[j] = &Bs[wave * 8 + j * 32][0];
  }
  f32x4 acc[4][4] = {};
  for (int k0 = 0; k0 < K; k0 += 64) {
    __syncthreads();
    for (int j = 0; j < 4; j++) {
      async_copy16(Ap[j] + k0, lA[j]);
      async_copy16(Bp[j] + k0, lB[j]);
    }
    __syncthreads();
    for (int ks = 0; ks < 2; ks++) {
      bf16x8 af[4], bfv[4];
      for (int i = 0; i < 4; i++) {
        int ra = wm + i * 16 + lrow, rb = wn + i * 16 + lrow;
        af[i]  = *(const bf16x8*)&As[ra][(((ks * 4 + quad) ^ (ra & 7))) * 8];
        bfv[i] = *(const bf16x8*)&Bs[rb][(((ks * 4 + quad) ^ (rb & 7))) * 8];
      }
      for (int mi = 0; mi < 4; mi++)
        for (int ni = 0; ni < 4; ni++)
          acc[mi][ni] = __builtin_amdgcn_mfma_f32_16x16x32_bf16(af[mi], bfv[ni], acc[mi][ni], 0, 0, 0);
    }
  }
  for (int ni = 0; ni < 4; ni++) {
    int col = n0 + wn + ni * 16 + lrow;
    float bv = bias[col];
    for (int mi = 0; mi < 4; mi++) {
      int row = m0 + wm + mi * 16 + quad * 4;
      for (int r = 0; r < 4; r++) {
        float v = acc[mi][ni][r] + bv;
        if (RELU) v = fmaxf(v, 0.f);
        C[(size_t)(row + r) * N + col] = (OutT)v;
      }
    }
  }
}

// ---------------- bf16 TN GEMM, 256x256 8-phase counted-vmcnt pipeline ----------------
// Guide §5 "256² 8-phase" template (T3+T4 counted vmcnt + T5 setprio), derived schedule.
// BM=BN=256, BK=64, 512 thr = 8 waves (2M x 4N, per-wave 128x64), LDS 128 KiB
// (2 dbuf x [256][64] bf16 for A and B), 16B-granule XOR swizzle (same as k_gemm).
// Requires M%256==0, N%256==0, K%128==0. Numerics identical to k_gemm (same per-acc
// accumulation order: per K-tile ks0 then ks1).
// Stage halves (2 x global_load_lds each): A-H0={s0,s1} rows 0-127, A-H1={s2,s3},
// B-H2={s0,s1}, B-H3={s2,s3}. Per tile kt (buf c=kt&1) 4 phases:
//  ph0: read B[ks0]+A[ks0,mi0-3] | stage (kt+1,A-H0)->c^1 | bar; lgkm0; 16 mfma; bar
//  ph1: read A[ks0,mi4-7]        | stage (kt+1,A-H1)->c^1 | bar; lgkm0; 16 mfma; bar
//  ph2: read B[ks1]+A[ks1,mi0-3] | stage (kt+1,B-H3)->c^1 | bar; lgkm0; 16 mfma; bar
//  ph3: read A[ks1,mi4-7]        | stage (kt+2,B-H2)->c   | bar; lgkm0; 16 mfma;
//       vmcnt(2 if kt+2<nt else 0); bar
// Invariants (re-verified r8): every stage target's last reader drained lgkm before
// the barrier preceding the stage issue; end-of-ph3 vmcnt(2) retires all but the
// newest half (kt+2,B-H2), so every tile-(kt+1) half is landed before its ph0 reads;
// all barriers wave-uniform (no divergent-barrier hang).
template<bool RELU, typename OutT>
__global__ __launch_bounds__(512, 2) void k_gemm2(const __bf16* __restrict__ A,
    const __bf16* __restrict__ Bt, const float* __restrict__ bias,
    OutT* __restrict__ C, int M, int N, int K) {
  __shared__ __bf16 As[2][256][64];
  __shared__ __bf16 Bs[2][256][64];
  const int m0 = blockIdx.y * 256, n0 = blockIdx.x * 256;
  const int t = threadIdx.x;
  const int wid = t >> 6, lane = t & 63;
  const int wr = wid >> 2, wc = wid & 3;
  const int lrow = lane & 15, quad = lane >> 4;
  const int r8 = lane >> 3;
  const int gG = (lane & 7) ^ (r8 & 7);
  const __bf16* aS[4]; const __bf16* bS[4];
  #pragma unroll
  for (int s = 0; s < 4; s++) {
    const int row = s * 64 + wid * 8 + r8;
    aS[s] = A  + (size_t)(m0 + row) * K + gG * 8;
    bS[s] = Bt + (size_t)(n0 + row) * K + gG * 8;
  }
#define STG_A(c_, s_, kt_) async_copy16(aS[s_] + (size_t)(kt_) * 64, &As[c_][(s_) * 64 + wid * 8][0])
#define STG_B(c_, s_, kt_) async_copy16(bS[s_] + (size_t)(kt_) * 64, &Bs[c_][(s_) * 64 + wid * 8][0])
#define LDA2(c_, mi_, ks_) ({ const int ra_ = wr * 128 + (mi_) * 16 + lrow; \
    *(const bf16x8*)&As[c_][ra_][(((ks_) * 4 + quad) ^ (ra_ & 7)) * 8]; })
#define LDB2(c_, ni_, ks_) ({ const int rb_ = wc * 64 + (ni_) * 16 + lrow; \
    *(const bf16x8*)&Bs[c_][rb_][(((ks_) * 4 + quad) ^ (rb_ & 7)) * 8]; })
#define GBAR __builtin_amdgcn_s_barrier()
#define LGKM0 { asm volatile("s_waitcnt lgkmcnt(0)" ::: "memory"); __builtin_amdgcn_sched_barrier(0); }
  f32x4 acc[8][4] = {};
  const int nt = K >> 6;  // >= 2 required (K >= 128)
  // prologue: tile0 all halves + (tile1, B-H2); vmcnt(2) leaves only the latter in flight
  STG_A(0, 0, 0); STG_A(0, 1, 0); STG_A(0, 2, 0); STG_A(0, 3, 0);
  STG_B(0, 0, 0); STG_B(0, 1, 0); STG_B(0, 2, 0); STG_B(0, 3, 0);
  STG_B(1, 0, 1); STG_B(1, 1, 1);
  asm volatile("s_waitcnt vmcnt(2)" ::: "memory");
  GBAR;
  for (int kt = 0; kt < nt; kt++) {
    const int c = kt & 1, d = c ^ 1;
    const bool st1 = (kt + 1 < nt), st2 = (kt + 2 < nt);
    bf16x8 a[4], b[4];
    // ---- ph0 ----
    #pragma unroll
    for (int ni = 0; ni < 4; ni++) b[ni] = LDB2(c, ni, 0);
    #pragma unroll
    for (int mi = 0; mi < 4; mi++) a[mi] = LDA2(c, mi, 0);
    if (st1) { STG_A(d, 0, kt + 1); STG_A(d, 1, kt + 1); }
    GBAR; LGKM0;
    __builtin_amdgcn_s_setprio(1);
    #pragma unroll
    for (int mi = 0; mi < 4; mi++)
      #pragma unroll
      for (int ni = 0; ni < 4; ni++)
        acc[mi][ni] = __builtin_amdgcn_mfma_f32_16x16x32_bf16(a[mi], b[ni], acc[mi][ni], 0, 0, 0);
    __builtin_amdgcn_s_setprio(0);
    GBAR;
    // ---- ph1 ----
    #pragma unroll
    for (int mi = 0; mi < 4; mi++) a[mi] = LDA2(c, mi + 4, 0);
    if (st1) { STG_A(d, 2, kt + 1); STG_A(d, 3, kt + 1); }
    GBAR; LGKM0;
    __builtin_amdgcn_s_setprio(1);
    #pragma unroll
    for (int mi = 0; mi < 4; mi++)
      #pragma unroll
      for (int ni = 0; ni < 4; ni++)
        acc[mi + 4][ni] = __builtin_amdgcn_mfma_f32_16x16x32_bf16(a[mi], b[ni], acc[mi + 4][ni], 0, 0, 0);
    __builtin_amdgcn_s_setprio(0);
    GBAR;
    // ---- ph2 ----
    #pragma unroll
    for (int ni = 0; ni < 4; ni++) b[ni] = LDB2(c, ni, 1);
    #pragma unroll
    for (int mi = 0; mi < 4; mi++) a[mi] = LDA2(c, mi, 1);
    if (st1) { STG_B(d, 2, kt + 1); STG_B(d, 3, kt + 1); }
    GBAR; LGKM0;
    __builtin_amdgcn_s_setprio(1);
    #pragma unroll
    for (int mi = 0; mi < 4; mi++)
      #pragma unroll
      for (int ni = 0; ni < 4; ni++)
        acc[mi][ni] = __builtin_amdgcn_mfma_f32_16x16x32_bf16(a[mi], b[ni], acc[mi][ni], 0, 0, 0);
    __builtin_amdgcn_s_setprio(0);
    GBAR;
    // ---- ph3 ----
    #pragma unroll
    for (int mi = 0; mi < 4; mi++) a[mi] = LDA2(c, mi + 4, 1);
    if (st2) { STG_B(c, 0, kt + 2); STG_B(c, 1, kt + 2); }
    GBAR; LGKM0;
    __builtin_amdgcn_s_setprio(1);
    #pragma unroll
    for (int mi = 0; mi < 4; mi++)
      #pragma unroll
      for (int ni = 0; ni < 4; ni++)
        acc[mi + 4][ni] = __builtin_amdgcn_mfma_f32_16x16x32_bf16(a[mi], b[ni], acc[mi + 4][ni], 0, 0, 0);
    __builtin_amdgcn_s_setprio(0);
    if (st2) { asm volatile("s_waitcnt vmcnt(2)" ::: "memory"); }
    else     { asm volatile("s_waitcnt vmcnt(0)" ::: "memory"); }
    GBAR;
  }
  #pragma unroll
  for (int ni = 0; ni < 4; ni++) {
    const int col = n0 + wc * 64 + ni * 16 + lrow;
    const float bv = bias[col];
    #pragma unroll
    for (int mi = 0; mi < 8; mi++) {
      const int row = m0 + wr * 128 + mi * 16 + quad * 4;
      #pragma unroll
      for (int r = 0; r < 4; r++) {
        float v = acc[mi][ni][r] + bv;
        if (RELU) v = fmaxf(v, 0.f);
        C[(size_t)(row + r) * N + col] = (OutT)v;
      }
    }
  }
#undef STG_A
#undef STG_B
#undef LDA2
#undef LDB2
#undef GBAR
#undef LGKM0
}

// ---------------- fused flash attention v3 (FROZEN at 653.9us baseline form) ----------
// grid (Lq/128, B*H). Causal: block bx covers q-tiles (bx, NT-1-bx); cross: (2bx, 2bx+1).
// Each wave: 16 q-rows per tile. Softmax in exp2 domain (scale*log2e folded into Q).
// PERF LEDGER — 5 variants failed for 5 measured reasons; kernel is at a register
// knife edge AND its LDS V-staging is the right latency tier. DO NOT micro-edit:
//  - vfr[4][4] V-frag hoist across f: scratch spill, +350MB HBM r/w, 101->231us (r2).
//  - s_setprio around MFMA clusters: spill via code-motion barrier, 101->162us (r3).
//  - deferred l-sum: f0/f1 live-range overlap -> spill, +112MB FETCH, 101->131us (r5).
//  - permlane16_swap max-reduce + defer-max (r1, bundled): absmax fail 0.36.
//  - V from pre-transposed global (no LDS): uncoalesced 8B PV loads, latency-bound,
//    MfmaUtil 20->12%, 101->168us (r7).
template<bool CAUSAL>
__global__ __launch_bounds__(256, 4) void k_attn(const __bf16* __restrict__ Q,
    const __bf16* __restrict__ Kg, const __bf16* __restrict__ Vg,
    float* __restrict__ O, int Lq, int Lk, int qs, int kvs) {
  __shared__ alignas(16) __bf16   Ks[2][64][72];
  __shared__ alignas(16) uint16_t Vt[2][64][72];   // [vd][k]
  const int t = threadIdx.x;
  const int wave = t >> 6, lane = t & 63;
  const int lrow = lane & 15, quad = lane >> 4;
  const int wm16 = wave * 16;
  int qt[2];
  if (CAUSAL) { qt[0] = blockIdx.x; qt[1] = gridDim.x * 2 - 1 - blockIdx.x; }
  else        { qt[0] = blockIdx.x * 2; qt[1] = qt[0] + 1; }
  const int b = blockIdx.y >> 4, h = blockIdx.y & 15;
  const __bf16* Qb = Q  + (size_t)b * Lq * qs  + h * DHEAD;
  const __bf16* Kb = Kg + (size_t)b * Lk * kvs + h * DHEAD;
  const __bf16* Vb = Vg + (size_t)b * Lk * kvs + h * DHEAD;
  // Q B-fragments, scale folded: 0.125 * log2(e) (softmax done in exp2 domain)
  const float qsc = 0.125f * 1.44269504f;
  bf16x8 qf[2][2];
  for (int f = 0; f < 2; f++)
    for (int ks = 0; ks < 2; ks++) {
      U128 u;
      u.u = *(const uint4*)(Qb + (size_t)(qt[f] * 64 + wm16 + lrow) * qs + ks * 32 + quad * 8);
      for (int j = 0; j < 8; j++) u.h[j] = (__bf16)((float)u.h[j] * qsc);
      qf[f][ks] = *(const bf16x8*)u.h;
    }
  const int nkt = CAUSAL ? (qt[1] + 1) : (Lk / 64);
  const int krow = t >> 3, kcol = (t & 7) * 8;
  const int vkk = t & 63;
  f32x4 acc_o[2][4] = {};       // O^T per frag: row vd=ni*16+quad*4+r, col q=lrow
  float m_r[2] = {-1e30f, -1e30f}, l_r[2] = {0.f, 0.f};
  uint4 ka, ka2, va, va2;
  ka  = *(const uint4*)(Kb + (size_t)krow * kvs + kcol);
  ka2 = *(const uint4*)(Kb + (size_t)(krow + 32) * kvs + kcol);
  va  = *(const uint4*)(Vb + (size_t)vkk * kvs + wave * 8);
  va2 = *(const uint4*)(Vb + (size_t)vkk * kvs + (wave + 4) * 8);
  int c = 0;
  for (int kt = 0; kt < nkt; kt++) {
    const int kn = (kt + 1 < nkt) ? (kt + 1) * 64 : kt * 64;
    uint4 na  = *(const uint4*)(Kb + (size_t)(kn + krow) * kvs + kcol);
    uint4 na2 = *(const uint4*)(Kb + (size_t)(kn + krow + 32) * kvs + kcol);
    uint4 nv  = *(const uint4*)(Vb + (size_t)(kn + vkk) * kvs + wave * 8);
    uint4 nv2 = *(const uint4*)(Vb + (size_t)(kn + vkk) * kvs + (wave + 4) * 8);
    *(uint4*)&Ks[c][krow][kcol]      = ka;
    *(uint4*)&Ks[c][krow + 32][kcol] = ka2;
    { U128 u; u.u = va;  for (int j = 0; j < 8; j++) Vt[c][wave * 8 + j][vkk] = pv_bits(u.h[j]); }
    { U128 u; u.u = va2; for (int j = 0; j < 8; j++) Vt[c][(wave + 4) * 8 + j][vkk] = pv_bits(u.h[j]); }
    __syncthreads();
    for (int f = 0; f < 2; f++) {
      if (CAUSAL && kt > qt[f]) continue;   // wave-uniform: fully-masked sub-tile
      // S^T = K Q^T : C-layout row k=nb*16+quad*4+r, col q=lrow  (exp2 domain)
      f32x4 st[4] = {};
      for (int ks = 0; ks < 2; ks++)
        for (int nb = 0; nb < 4; nb++) {
          bf16x8 kf = *(const bf16x8*)&Ks[c][nb * 16 + lrow][ks * 32 + quad * 8];
          st[nb] = __builtin_amdgcn_mfma_f32_16x16x32_bf16(kf, qf[f][ks], st[nb], 0, 0, 0);
        }
      float pm = -1e30f;
      for (int nb = 0; nb < 4; nb++)
        for (int r = 0; r < 4; r++) {
          float s = st[nb][r];
          if (CAUSAL && kt == qt[f])
            if (nb * 16 + quad * 4 + r > wm16 + lrow) s = -1e30f;
          st[nb][r] = s;
          pm = fmaxf(pm, s);
        }
      pm = fmaxf(pm, __shfl_xor(pm, 16));
      pm = fmaxf(pm, __shfl_xor(pm, 32));
      float mn = fmaxf(m_r[f], pm);
      float alpha = exp2f(m_r[f] - mn);
      m_r[f] = mn;
      float rs = 0.f;
      PV4 pf[4];
      for (int nb = 0; nb < 4; nb++) {
        float p0 = exp2f(st[nb][0] - mn), p1 = exp2f(st[nb][1] - mn);
        float p2 = exp2f(st[nb][2] - mn), p3 = exp2f(st[nb][3] - mn);
        rs += (p0 + p1) + (p2 + p3);
        pf[nb] = pack4(p0, p1, p2, p3);
      }
      rs += __shfl_xor(rs, 16);
      rs += __shfl_xor(rs, 32);
      l_r[f] = l_r[f] * alpha + rs;
      for (int ni = 0; ni < 4; ni++)
        for (int r = 0; r < 4; r++) acc_o[f][ni][r] *= alpha;
      // O^T += V^T P^T  (A = V^T frag from LDS b64, B = P frag from registers)
      for (int nb = 0; nb < 4; nb++)
        for (int ni = 0; ni < 4; ni++) {
          PV4 vf; vf.u = *(const uint2*)&Vt[c][ni * 16 + lrow][nb * 16 + quad * 4];
          acc_o[f][ni] = mfma16(vf, pf[nb], acc_o[f][ni]);
        }
    }
    ka = na; ka2 = na2; va = nv; va2 = nv2;
    c ^= 1;
  }
  for (int f = 0; f < 2; f++) {
    const float linv = 1.f / fmaxf(l_r[f], 1e-30f);
    float* orow = O + (size_t)b * Lq * DMODEL
                + (size_t)(qt[f] * 64 + wm16 + lrow) * DMODEL + h * DHEAD;
    for (int ni = 0; ni < 4; ni++) {
      float4 v = { acc_o[f][ni][0] * linv, acc_o[f][ni][1] * linv,
                   acc_o[f][ni][2] * linv, acc_o[f][ni][3] * linv };
      *(float4*)(orow + ni * 16 + quad * 4) = v;
    }
  }
}

// ---------------- residual(ResT + fp32) + LayerNorm -> OutT ----------------
template<typename ResT, typename OutT>
__global__ __launch_bounds__(256) void k_ln_add(const ResT* __restrict__ a,
    const float* __restrict__ bres, const float* __restrict__ g,
    const float* __restrict__ be, OutT* __restrict__ out) {
  __shared__ float red[2][4];
  const int r = blockIdx.x, t = threadIdx.x;
  const size_t base = (size_t)r * DMODEL + t * 4;
  float x[4];
  for (int i = 0; i < 4; i++) x[i] = (float)a[base + i] + bres[base + i];
  float s  = x[0] + x[1] + x[2] + x[3];
  float s2 = x[0]*x[0] + x[1]*x[1] + x[2]*x[2] + x[3]*x[3];
  for (int off = 32; off > 0; off >>= 1) {
    s  += __shfl_down(s, off);
    s2 += __shfl_down(s2, off);
  }
  if ((t & 63) == 0) { red[0][t >> 6] = s; red[1][t >> 6] = s2; }
  __syncthreads();
  s  = red[0][0] + red[0][1] + red[0][2] + red[0][3];
  s2 = red[1][0] + red[1][1] + red[1][2] + red[1][3];
  const float mean = s * (1.f / DMODEL);
  const float var  = s2 * (1.f / DMODEL) - mean * mean;
  const float rstd = rsqrtf(var + 1e-5f);
  for (int i = 0; i < 4; i++)
    out[base + i] = (OutT)((x[i] - mean) * rstd * g[t * 4 + i] + be[t * 4 + i]);
}

extern "C" void kernel_launch(void* const* d_in, const int* in_sizes, int n_in,
                              void* d_out, int out_size, void* d_ws, size_t ws_size,
                              hipStream_t stream) {
  (void)in_sizes; (void)n_in; (void)out_size; (void)ws_size;
  const float* dec   = (const float*)d_in[0];
  const float* enc   = (const float*)d_in[1];
  const float* m_wq  = (const float*)d_in[2];
  const float* m_bq  = (const float*)d_in[3];
  const float* m_wk  = (const float*)d_in[4];
  const float* m_bk  = (const float*)d_in[5];
  const float* m_wv  = (const float*)d_in[6];
  const float* m_bv  = (const float*)d_in[7];
  const float* c_wq  = (const float*)d_in[8];
  const float* c_bq  = (const float*)d_in[9];
  const float* c_wk  = (const float*)d_in[10];
  const float* c_bk  = (const float*)d_in[11];
  const float* c_wv  = (const float*)d_in[12];
  const float* c_bv  = (const float*)d_in[13];
  const float* ff_w1 = (const float*)d_in[14];
  const float* ff_b1 = (const float*)d_in[15];
  const float* ff_w2 = (const float*)d_in[16];
  const float* ff_b2 = (const float*)d_in[17];
  const float* ln1_g = (const float*)d_in[18];
  const float* ln1_b = (const float*)d_in[19];
  const float* ln2_g = (const float*)d_in[20];
  const float* ln2_b = (const float*)d_in[21];

  // workspace (136 MB):
  //  [0,16)   decB -> X1b          [16,32)  encB -> X2b
  //  [32,40)  WB weights (bf16); fp32 bias pack at +38MB
  //  [40,88)  QKV (self) | [40,72) KV (cross) + [72,88) Qc | [40,104) FF
  //  [104,136) AO (fp32)
  char* w = (char*)d_ws;
  __bf16* decB = (__bf16*)(w);
  __bf16* encB = (__bf16*)(w + (16ull << 20));
  __bf16* X1b  = decB;
  __bf16* X2b  = encB;
  __bf16* WB   = (__bf16*)(w + (32ull << 20));
  float*  BP   = (float*) (w + (38ull << 20));
  __bf16* QKV  = (__bf16*)(w + (40ull << 20));
  __bf16* KV   = (__bf16*)(w + (40ull << 20));
  __bf16* Qc   = (__bf16*)(w + (72ull << 20));
  __bf16* FF   = (__bf16*)(w + (40ull << 20));
  float*  AO   = (float*) (w + (104ull << 20));
  float* out = (float*)d_out;

  const int M = 8192, NTOK = M * DMODEL;
  dim3 blk(256);
  dim3 blk2(512);
  dim3 gT3(2, 32, 48);    // 3-source per-head weight transpose
  dim3 gA(8, 128);        // attention: 2 q-tiles per block
  dim3 gL(M);

  k_cast2<<<dim3(2 * NTOK / 1024), blk, 0, stream>>>(dec, enc, decB, encB, NTOK);

  // ---- masked self-attention: fused QKV projection (N=3072) ----
  k_transpose3<<<gT3, blk, 0, stream>>>(m_wq, m_wk, m_wv, WB, 1024, 64);
  k_pack<<<dim3(12), blk, 0, stream>>>(BP, m_bq, m_bk, m_bv, 1024);
  k_gemm2<false, __bf16><<<dim3(12, 32), blk2, 0, stream>>>(decB, WB, BP, QKV, M, 3072, 1024);
  k_attn<true><<<gA, blk, 0, stream>>>(QKV, QKV + 1024, QKV + 2048, AO, 1024, 1024, 3072, 3072);
  k_ln_add<float, __bf16><<<gL, blk, 0, stream>>>(dec, AO, ln1_g, ln1_b, X1b);  // decB dead

  // ---- cross-attention: fused KV (N=2048, enc) + Q (X1b) ----
  k_transpose3<<<gT3, blk, 0, stream>>>(c_wk, c_wv, c_wq, WB, 1024, 64);
  k_pack<<<dim3(8), blk, 0, stream>>>(BP, c_bk, c_bv, c_bv, 1024);
  k_gemm2<false, __bf16><<<dim3(8, 32), blk2, 0, stream>>>(encB, WB, BP, KV, M, 2048, 1024);
  k_gemm<false, __bf16><<<dim3(8, 64), blk, 0, stream>>>(X1b, WB + (2 << 20), c_bq, Qc, M, 1024, 1024);
  k_attn<false><<<gA, blk, 0, stream>>>(Qc, KV, KV + 1024, AO, 1024, 1024, 1024, 2048);
  k_ln_add<__bf16, __bf16><<<gL, blk, 0, stream>>>(X1b, AO, ln2_g, ln2_b, X2b);  // encB dead

  // ---- FFN (QKV/KV/Qc dead -> FF overlays [40,104)) ----
  k_transpose<<<dim3(128, 32, 1), blk, 0, stream>>>(ff_w1, WB, 1024, 4096);
  k_gemm2<true, __bf16><<<dim3(16, 32), blk2, 0, stream>>>(X2b, WB, ff_b1, FF, M, 4096, 1024);
  k_transpose<<<dim3(32, 128, 1), blk, 0, stream>>>(ff_w2, WB, 4096, 1024);
  k_gemm<false, float><<<dim3(8, 64), blk, 0, stream>>>(FF, WB, ff_b2, AO, M, 1024, 4096);
  k_ln_add<__bf16, float><<<gL, blk, 0, stream>>>(X2b, AO, ln2_g, ln2_b, out);
}